// Round 10
// baseline (298.955 us; speedup 1.0000x reference)
//
#include <hip/hip_runtime.h>

// Geometry
constexpr int   NX    = 96;
constexpr int   SY    = 96;
constexpr int   SZ    = 96 * 96;
constexpr int   VOL   = 96 * 96 * 96;
constexpr int   NT_IN = 8;
constexpr int   NT    = 7;
constexpr int   NB    = 2;
constexpr int   NTOT  = NB * NT * VOL;       // 12386304
constexpr int   TX    = 24;                  // threads along x (4 floats each = full 96 row)
constexpr int   TY    = 8;                   // rows per block tile
constexpr int   BLK   = TX * TY;             // 192 threads = 3 waves
constexpr int   ZC    = 16;                  // z planes marched per block
constexpr int   NZC   = NX / ZC;             // 6
constexpr int   NYG   = NX / TY;             // 12
constexpr int   NBLK  = NB * NT * NZC * NYG; // 1008 blocks

// LDS layout (floats)
constexpr int   RINGP = TY * 96;             // 768 floats per ring plane (center rows only)
constexpr int   RING0 = 0;                   // 6 ring planes
constexpr int   HALO0 = 6 * RINGP;           // 4608
constexpr int   HALOSZ= 4 * 96;              // 384 (rows y0-2,y0-1,y0+8,y0+9)
constexpr int   UY0   = HALO0 + 2 * HALOSZ;  // 5376
constexpr int   UYSZ  = 10 * 96;             // 960 (rows y0-1..y0+8)
constexpr int   UZ0   = UY0 + 2 * UYSZ;      // 7296
constexpr int   UZSZ  = TY * 96;             // 768
constexpr int   LDSF  = UZ0 + 2 * UZSZ;      // 8832 floats = 35328 B

constexpr float DTI    = 100.0f;
constexpr float INVH   = 10.0f;
constexpr float INV2H  = 5.0f;
constexpr float INV2H2 = 50.0f;
constexpr float INV4H2 = 25.0f;
constexpr float D_EFF  = 0.001f;

__device__ __forceinline__ void ld4(float* d, const float* __restrict__ p) {
    *(float4*)d = *(const float4*)p;
}

// 5-tap weights for gradient(gradient(.)) over taps (m2,m1,c,p1,p2), axis size 96.
// Zero-weight taps multiply clamped (finite) values -> contribute exactly 0.
__device__ __forceinline__ void wts5(int i, float* w) {
    if (i == 0)       { w[0]=0.f;     w[1]=0.f;          w[2]=INV2H2;       w[3]=-2.f*INV2H2; w[4]=INV2H2; }
    else if (i == 1)  { w[0]=0.f;     w[1]=2.f*INV4H2;   w[2]=-3.f*INV4H2;  w[3]=0.f;         w[4]=INV4H2; }
    else if (i == 94) { w[0]=INV4H2;  w[1]=0.f;          w[2]=-3.f*INV4H2;  w[3]=2.f*INV4H2;  w[4]=0.f;    }
    else if (i == 95) { w[0]=INV2H2;  w[1]=-2.f*INV2H2;  w[2]=INV2H2;       w[3]=0.f;         w[4]=0.f;    }
    else              { w[0]=INV4H2;  w[1]=0.f;          w[2]=-2.f*INV4H2;  w[3]=0.f;         w[4]=INV4H2; }
}

__global__ __launch_bounds__(BLK) void resid_kernel(
    const float* __restrict__ c_pred, const float* __restrict__ u_future,
    const float* __restrict__ mask, float* __restrict__ partial) {
    __shared__ __align__(16) float lds[LDSF + 32];   // +pad: harmless OOB window reads at tile corners

    const int tid = threadIdx.x;
    const int tx  = tid % TX;        // 0..23
    const int ty  = tid / TX;        // 0..7

    int bid = blockIdx.x;
    const int yg = bid % NYG;  bid /= NYG;
    const int zc = bid % NZC;  bid /= NZC;
    const int t  = bid % NT;
    const int b  = bid / NT;
    const int z0 = zc * ZC;
    const int y0 = yg * TY;
    const int y  = y0 + ty;
    const int xb = tx * 4;
    const int vcg = y * SY + xb;     // own in-plane global offset

    const float* ct   = c_pred + (size_t)(b * NT_IN + t + 1) * VOL;
    const float* ctm1 = ct - VOL;
    const float* uxB  = u_future + (size_t)((b * NT_IN + t + 1) * 3) * VOL;
    const float* uyB  = uxB + VOL;
    const float* uzB  = uyB + VOL;
    const float* mkB  = mask + (size_t)b * VOL;

    // ---- per-thread hoisted constants ----
    float wy[5];
    wts5(y, wy);
    const float fy = (y == 0 || y == 95) ? INVH : INV2H;
    const int intra_c = ty * 96 + xb;             // own position inside a ring plane / uz tile

    // y-tap LDS addressing: intra offset + which buffer (ring plane vs halo)
    int  tIntra[4];  bool tInRing[4];
    {
        const int dys[4] = {-2, -1, 1, 2};
        #pragma unroll
        for (int k = 0; k < 4; ++k) {
            int yt = y + dys[k]; yt = yt < 0 ? 0 : (yt > 95 ? 95 : yt);
            bool inT = (yt >= y0) && (yt < y0 + TY);
            int hr = (yt < y0) ? (yt - (y0 - 2)) : (yt - (y0 + TY) + 2);
            tInRing[k] = inT;
            tIntra[k]  = (inT ? (yt - y0) * 96 : hr * 96) + xb;
        }
    }
    // halo staging row map (threads 0..95)
    const int h_hr  = tid / 24;
    const int h_col = (tid % 24) * 4;
    int h_gy = (h_hr < 2) ? (y0 - 2 + h_hr) : (y0 + 6 + h_hr);
    h_gy = h_gy < 0 ? 0 : (h_gy > 95 ? 95 : h_gy);
    // uy staging rows (all threads; threads <48 do a second one)
    const int uy_br0 = tid / 24;                 // 0..7
    const int uy_br1 = 8 + tid / 24;             // 8..9 for tid<48
    int uy_g0 = y0 - 1 + uy_br0; uy_g0 = uy_g0 < 0 ? 0 : (uy_g0 > 95 ? 95 : uy_g0);
    int uy_g1 = y0 - 1 + uy_br1; uy_g1 = uy_g1 > 95 ? 95 : uy_g1;
    const int uy_col = (tid % 24) * 4;

    // ---- prologue: stage ring planes z0-2..z0+2, halo/uy/uz for plane z0 ----
    #pragma unroll
    for (int k = -2; k <= 2; ++k) {
        int p = z0 + k;
        int slot = (p + 6) % 6;
        int pc = p < 0 ? 0 : (p > 95 ? 95 : p);
        float v[4]; ld4(v, ct + pc * SZ + vcg);
        *(float4*)&lds[RING0 + slot * RINGP + intra_c] = *(float4*)v;
    }
    {
        int ps = z0 & 1;
        if (tid < 96) {
            float v[4]; ld4(v, ct + z0 * SZ + h_gy * SY + h_col);
            *(float4*)&lds[HALO0 + ps * HALOSZ + h_hr * 96 + h_col] = *(float4*)v;
        }
        float v0[4]; ld4(v0, uyB + z0 * SZ + uy_g0 * SY + uy_col);
        *(float4*)&lds[UY0 + ps * UYSZ + uy_br0 * 96 + uy_col] = *(float4*)v0;
        if (tid < 48) {
            float v1[4]; ld4(v1, uyB + z0 * SZ + uy_g1 * SY + uy_col);
            *(float4*)&lds[UY0 + ps * UYSZ + uy_br1 * 96 + uy_col] = *(float4*)v1;
        }
        float vz[4]; ld4(vz, uzB + z0 * SZ + vcg);
        *(float4*)&lds[UZ0 + ps * UZSZ + intra_c] = *(float4*)vz;
    }
    __syncthreads();

    float acc = 0.0f;

    for (int iz = 0; iz < ZC; ++iz) {
        const int z  = z0 + iz;
        const int ps = z & 1, ps1 = (z + 1) & 1;
        const int zm = (z > 0)  ? z - 1 : 0;
        const int zp = (z < 95) ? z + 1 : 95;
        const int pnext = (z + 1 > 95) ? 95 : z + 1;   // staged-next plane (clamped)
        const int pring = (z + 3 > 95) ? 95 : z + 3;

        // ---- issue all global loads first (direct + staging) ----
        float uxm[4], uxp[4], cm1[4], mv[4];
        ld4(uxm, uxB + zm * SZ + vcg);
        ld4(uxp, uxB + zp * SZ + vcg);
        ld4(cm1, ctm1 + z * SZ + vcg);
        ld4(mv,  mkB + z * SZ + vcg);
        float rg[4], hl[4], uya[4], uyb2[4], uzs[4];
        ld4(rg, ct + pring * SZ + vcg);
        if (tid < 96) ld4(hl, ct + pnext * SZ + h_gy * SY + h_col);
        ld4(uya, uyB + pnext * SZ + uy_g0 * SY + uy_col);
        if (tid < 48) ld4(uyb2, uyB + pnext * SZ + uy_g1 * SY + uy_col);
        ld4(uzs, uzB + pnext * SZ + vcg);

        // ---- LDS reads for this step ----
        const int s_c  = z % 6;
        const int s_m1 = (z + 5) % 6, s_p1 = (z + 1) % 6;
        const int s_m2 = (z + 4) % 6, s_p2 = (z + 2) % 6;
        const int base_c = RING0 + s_c * RINGP;

        float cc[4], czm1[4], czp1[4], czm2[4], czp2[4];
        *(float4*)cc   = *(float4*)&lds[base_c + intra_c];
        *(float4*)czm1 = *(float4*)&lds[RING0 + s_m1 * RINGP + intra_c];
        *(float4*)czp1 = *(float4*)&lds[RING0 + s_p1 * RINGP + intra_c];
        *(float4*)czm2 = *(float4*)&lds[RING0 + s_m2 * RINGP + intra_c];
        *(float4*)czp2 = *(float4*)&lds[RING0 + s_p2 * RINGP + intra_c];

        float yt0[4], yt1[4], yt2[4], yt3[4];   // c at y-2,y-1,y+1,y+2
        {
            const int hbase = HALO0 + ps * HALOSZ;
            *(float4*)yt0 = *(float4*)&lds[(tInRing[0] ? base_c : hbase) + tIntra[0]];
            *(float4*)yt1 = *(float4*)&lds[(tInRing[1] ? base_c : hbase) + tIntra[1]];
            *(float4*)yt2 = *(float4*)&lds[(tInRing[2] ? base_c : hbase) + tIntra[2]];
            *(float4*)yt3 = *(float4*)&lds[(tInRing[3] ? base_c : hbase) + tIntra[3]];
        }

        float axl[2], axr[2];
        {
            int ol = (tx > 0)      ? intra_c - 2 : intra_c;   // unused values at edges
            int orr = (tx < TX - 1) ? intra_c + 4 : intra_c;
            *(float2*)axl = *(float2*)&lds[base_c + ol];
            *(float2*)axr = *(float2*)&lds[base_c + orr];
        }

        float uym[4], uyp[4];
        *(float4*)uym = *(float4*)&lds[UY0 + ps * UYSZ + (ty + 0) * 96 + xb];
        *(float4*)uyp = *(float4*)&lds[UY0 + ps * UYSZ + (ty + 2) * 96 + xb];

        float uzc[4], uzl[2], uzr[2];
        {
            const int ub = UZ0 + ps * UZSZ;
            *(float4*)uzc = *(float4*)&lds[ub + intra_c];
            int ol = (tx > 0)      ? intra_c - 2 : intra_c;
            int orr = (tx < TX - 1) ? intra_c + 4 : intra_c;
            *(float2*)uzl = *(float2*)&lds[ub + ol];
            *(float2*)uzr = *(float2*)&lds[ub + orr];
        }

        // ---- compute ----
        float wz[5];
        wts5(z, wz);
        const float fz = (z == 0 || z == 95) ? INVH : INV2H;

        float ax[8], uzw[8];
        ax[0] = axl[0]; ax[1] = axl[1];
        ax[2] = cc[0];  ax[3] = cc[1];  ax[4] = cc[2];  ax[5] = cc[3];
        ax[6] = axr[0]; ax[7] = axr[1];
        uzw[0] = uzl[0]; uzw[1] = uzl[1];
        uzw[2] = uzc[0]; uzw[3] = uzc[1]; uzw[4] = uzc[2]; uzw[5] = uzc[3];
        uzw[6] = uzr[0]; uzw[7] = uzr[1];
        float P[7];
        #pragma unroll
        for (int k = 1; k <= 6; ++k) P[k] = uzw[k] * ax[k];

        float lx[4];
        #pragma unroll
        for (int j = 0; j < 4; ++j)
            lx[j] = (ax[j + 4] - 2.0f * ax[j + 2] + ax[j]) * INV4H2;
        if (tx == 0) {
            lx[0] = (ax[4] - 2.0f * ax[3] + ax[2]) * INV2H2;
            lx[1] = (ax[5] - 3.0f * ax[3] + 2.0f * ax[2]) * INV4H2;
        }
        if (tx == TX - 1) {
            lx[2] = (2.0f * ax[5] - 3.0f * ax[4] + ax[2]) * INV4H2;
            lx[3] = (ax[5] - 2.0f * ax[4] + ax[3]) * INV2H2;
        }

        #pragma unroll
        for (int j = 0; j < 4; ++j) {
            const float dc  = (cc[j] - cm1[j]) * DTI;
            const float fzv = (uxp[j] * czp1[j] - uxm[j] * czm1[j]) * fz;
            const float fyv = (uyp[j] * yt2[j] - uym[j] * yt1[j]) * fy;
            float fxv = (P[j + 3] - P[j + 1]) * INV2H;
            if (j == 0 && tx == 0)      fxv = (P[3] - P[2]) * INVH;
            if (j == 3 && tx == TX - 1) fxv = (P[5] - P[4]) * INVH;

            float lap = wz[0]*czm2[j] + wz[1]*czm1[j] + wz[2]*cc[j] + wz[3]*czp1[j] + wz[4]*czp2[j];
            lap += wy[0]*yt0[j] + wy[1]*yt1[j] + wy[2]*cc[j] + wy[3]*yt2[j] + wy[4]*yt3[j];
            lap += lx[j];

            const float r = (dc + fzv + fyv + fxv - D_EFF * lap) * mv[j];
            acc += r * r;
        }

        // ---- stage writes for future steps (slots not read this step) ----
        *(float4*)&lds[RING0 + ((z + 3) % 6) * RINGP + intra_c] = *(float4*)rg;
        if (tid < 96)
            *(float4*)&lds[HALO0 + ps1 * HALOSZ + h_hr * 96 + h_col] = *(float4*)hl;
        *(float4*)&lds[UY0 + ps1 * UYSZ + uy_br0 * 96 + uy_col] = *(float4*)uya;
        if (tid < 48)
            *(float4*)&lds[UY0 + ps1 * UYSZ + uy_br1 * 96 + uy_col] = *(float4*)uyb2;
        *(float4*)&lds[UZ0 + ps1 * UZSZ + intra_c] = *(float4*)uzs;

        __syncthreads();
    }

    // 3-wave block reduction
    #pragma unroll
    for (int off = 32; off > 0; off >>= 1) acc += __shfl_down(acc, off, 64);
    __shared__ float smem[3];
    const int lane = tid & 63, wid = tid >> 6;
    if (lane == 0) smem[wid] = acc;
    __syncthreads();
    if (tid == 0) partial[blockIdx.x] = smem[0] + smem[1] + smem[2];
}

__global__ __launch_bounds__(256) void final_reduce(
    const float* __restrict__ partial, int n, float* __restrict__ out) {
    float s = 0.0f;
    for (int i = threadIdx.x; i < n; i += 256) s += partial[i];
    #pragma unroll
    for (int off = 32; off > 0; off >>= 1) s += __shfl_down(s, off, 64);
    __shared__ float smem[4];
    const int lane = threadIdx.x & 63, wid = threadIdx.x >> 6;
    if (lane == 0) smem[wid] = s;
    __syncthreads();
    if (threadIdx.x == 0)
        out[0] = (smem[0] + smem[1] + smem[2] + smem[3]) * (1.0f / (float)NTOT);
}

extern "C" void kernel_launch(void* const* d_in, const int* in_sizes, int n_in,
                              void* d_out, int out_size, void* d_ws, size_t ws_size,
                              hipStream_t stream) {
    const float* c_pred   = (const float*)d_in[0];
    const float* u_future = (const float*)d_in[1];
    const float* mask     = (const float*)d_in[2];
    float* out     = (float*)d_out;
    float* partial = (float*)d_ws;

    resid_kernel<<<NBLK, BLK, 0, stream>>>(c_pred, u_future, mask, partial);
    final_reduce<<<1, 256, 0, stream>>>(partial, NBLK, out);
}